// Round 2
// baseline (1089.477 us; speedup 1.0000x reference)
//
#include <hip/hip_runtime.h>
#include <hip/hip_bf16.h>

// Problem constants (from reference)
#define Bn 4
#define Cc 256
#define Nn 2048
#define Ww 8
#define BLt 128     // tokens per block (N/BLOCKS)
#define NB 15       // blocks kept
#define Gg 120      // NB*W
#define TEMP 0.7f
#define INVTEMP (1.0f/0.7f)
#define EPSc 1e-6f

// ---------------- workspace in __device__ globals (avoids ws_size dependence) ----------
// layouts:
//  g_qt/g_kt/g_vt: [B][BL][G][C]  (k_t/v_t are sorted IN PLACE by sort_kernel)
//  g_val:          [B][G][BL][C]
__device__ float g_qt[Bn*BLt*Gg*Cc];
__device__ float g_kt[Bn*BLt*Gg*Cc];
__device__ float g_vt[Bn*BLt*Gg*Cc];
__device__ float g_val[Bn*Gg*BLt*Cc];
__device__ float g_sq[Bn*BLt*Gg];
__device__ float g_sk[Bn*BLt*Gg];
__device__ float g_R[Bn*Gg*Gg];
__device__ float g_perm[Bn*Gg*Gg];

// ---------------- K1: transpose  src[b,c,n,w] (n=blk*128+l, blk<15) -> dst[b,l,g=blk*8+w,c]
__global__ __launch_bounds__(256) void transpose_kernel(const float* __restrict__ src,
                                                        float* __restrict__ dst) {
    // grid: x = B*NB (60), y = lw-tile (16 of 64), z = c-tile (4 of 64)
    __shared__ float tile[64][65];
    int bblk = blockIdx.x;
    int b = bblk / NB, blk = bblk % NB;
    int lw0 = blockIdx.y * 64;
    int c0  = blockIdx.z * 64;
    int tx = threadIdx.x & 63;
    int ty = threadIdx.x >> 6;   // 0..3
    const float* sbase = src + (size_t)b * Cc * Nn * Ww + (size_t)blk * (BLt * Ww);
#pragma unroll
    for (int j = 0; j < 16; ++j) {
        int cl = ty + j * 4;
        tile[cl][tx] = sbase[(size_t)(c0 + cl) * (Nn * Ww) + lw0 + tx];
    }
    __syncthreads();
#pragma unroll
    for (int j = 0; j < 16; ++j) {
        int lwl = ty + j * 4;
        int lw = lw0 + lwl;
        int l = lw >> 3, w = lw & 7;
        size_t row = (size_t)(b * BLt + l) * Gg + blk * Ww + w;
        dst[row * Cc + c0 + tx] = tile[tx][lwl];
    }
}

// ---------------- K2: per-row mean over C for sq (from q_t) and sk (from k_t)
__global__ __launch_bounds__(256) void mean_kernel() {
    const long rows = (long)Bn * BLt * Gg;   // 61440
    int wave = threadIdx.x >> 6, lane = threadIdx.x & 63;
    long row = (long)blockIdx.x * 4 + wave;
    const float* src; float* dst; long r;
    if (row < rows) { src = g_qt; dst = g_sq; r = row; }
    else            { src = g_kt; dst = g_sk; r = row - rows; }
    if (r >= rows) return;
    const float* p = src + r * Cc;
    float s = p[lane] + p[lane + 64] + p[lane + 128] + p[lane + 192];
#pragma unroll
    for (int o = 32; o; o >>= 1) s += __shfl_down(s, o);
    if (lane == 0) dst[r] = s * (1.0f / Cc);
}

// ---------------- K3: R[b,i,j] = C^-0.5 * sum_l sq[b,l,i]*sk[b,l,j]
__global__ __launch_bounds__(256) void rmat_kernel() {
    int idx = blockIdx.x * 256 + threadIdx.x;
    if (idx >= Bn * Gg * Gg) return;
    int b = idx / (Gg * Gg);
    int r = idx % (Gg * Gg);
    int i = r / Gg, j = r % Gg;
    const float* pq = g_sq + (size_t)(b * BLt) * Gg + i;
    const float* pk = g_sk + (size_t)(b * BLt) * Gg + j;
    float acc = 0.f;
#pragma unroll 4
    for (int l = 0; l < BLt; ++l) acc += pq[(size_t)l * Gg] * pk[(size_t)l * Gg];
    g_R[idx] = acc * 0.0625f;   // 1/sqrt(256)
}

// ---------------- K4: gumbel-sinkhorn -> perm
__global__ void sinkhorn_kernel(const float* __restrict__ gumbel) {
    __shared__ float r[Gg][Gg + 1];
    int b = blockIdx.x, tid = threadIdx.x;   // 128 threads
    for (int idx = tid; idx < Gg * Gg; idx += 128) {
        int i = idx / Gg, j = idx % Gg;
        float x = g_R[b * Gg * Gg + idx];
        x = logf(fmaxf(x, 0.0f) + EPSc);
        r[i][j] = (x + gumbel[b * Gg * Gg + idx]) * INVTEMP;
    }
    for (int it = 0; it < 8; ++it) {
        __syncthreads();
        if (tid < Gg) {   // row logsumexp (axis=2 i.e. over j)
            float m = -1e30f;
            for (int j = 0; j < Gg; ++j) m = fmaxf(m, r[tid][j]);
            float s = 0.f;
            for (int j = 0; j < Gg; ++j) s += expf(r[tid][j] - m);
            float lse = m + logf(s);
            for (int j = 0; j < Gg; ++j) r[tid][j] -= lse;
        }
        __syncthreads();
        if (tid < Gg) {   // col logsumexp (axis=1 i.e. over i)
            float m = -1e30f;
            for (int i = 0; i < Gg; ++i) m = fmaxf(m, r[i][tid]);
            float s = 0.f;
            for (int i = 0; i < Gg; ++i) s += expf(r[i][tid] - m);
            float lse = m + logf(s);
            for (int i = 0; i < Gg; ++i) r[i][tid] -= lse;
        }
    }
    __syncthreads();
    for (int idx = tid; idx < Gg * Gg; idx += 128)
        g_perm[b * Gg * Gg + idx] = expf(r[idx / Gg][idx % Gg]);
}

// ---------------- K5: in-place sort of k_t and v_t:  X[l] <- perm^T @ X[l]  (per b,l)
__global__ __launch_bounds__(256) void sort_kernel() {
    // grid: x = B*BL (512), y = c-half (2), z = tensor (2: k, v)
    __shared__ float Xs[Gg][128];
    __shared__ float ps[Gg][Gg];
    float* buf = blockIdx.z ? g_vt : g_kt;
    int b = blockIdx.x / BLt, l = blockIdx.x % BLt;
    int c0 = blockIdx.y * 128;
    int tid = threadIdx.x;
    for (int idx = tid; idx < Gg * Gg; idx += 256)
        ps[idx / Gg][idx % Gg] = g_perm[b * Gg * Gg + idx];
    float* base = buf + ((size_t)(b * BLt + l) * Gg) * Cc + c0;
    for (int idx = tid; idx < Gg * 128; idx += 256) {
        int g = idx >> 7, c = idx & 127;
        Xs[g][c] = base[(size_t)g * Cc + c];
    }
    __syncthreads();
    int ft = tid >> 5;    // 0..7
    int ct = tid & 31;    // 0..31
    float acc[15][4];
#pragma unroll
    for (int s = 0; s < 15; ++s)
#pragma unroll
        for (int t = 0; t < 4; ++t) acc[s][t] = 0.f;
    for (int g = 0; g < Gg; ++g) {
        float xv0 = Xs[g][ct], xv1 = Xs[g][ct + 32], xv2 = Xs[g][ct + 64], xv3 = Xs[g][ct + 96];
#pragma unroll
        for (int s = 0; s < 15; ++s) {
            float pv = ps[g][ft + 8 * s];
            acc[s][0] += pv * xv0; acc[s][1] += pv * xv1;
            acc[s][2] += pv * xv2; acc[s][3] += pv * xv3;
        }
    }
    __syncthreads();
#pragma unroll
    for (int s = 0; s < 15; ++s) {
        int f = ft + 8 * s;
#pragma unroll
        for (int t = 0; t < 4; ++t) base[(size_t)f * Cc + ct + 32 * t] = acc[s][t];
    }
}

// ---------------- K6: attention per head (b,g): S=Q K^T/T, softmax, val = P V
__global__ __launch_bounds__(256) void attn_kernel() {
    __shared__ float S[128][129];
    __shared__ float Abuf[128 * 33];   // Q tile / V tile (32*132 == 128*33)
    __shared__ float Bbuf[128 * 33];   // K tile
    int hb = blockIdx.x;
    int b = hb / Gg, g = hb % Gg;
    const size_t rs = (size_t)Gg * Cc;  // row stride between l's
    const float* Q = g_qt + ((size_t)(b * BLt) * Gg + g) * Cc;
    const float* K = g_kt + ((size_t)(b * BLt) * Gg + g) * Cc;
    const float* V = g_vt + ((size_t)(b * BLt) * Gg + g) * Cc;
    int tid = threadIdx.x;
    int ti = tid >> 4, tj = tid & 15;

    // phase 1: S = (Q @ K^T) / TEMP
    float acc[8][8];
#pragma unroll
    for (int u = 0; u < 8; ++u)
#pragma unroll
        for (int v = 0; v < 8; ++v) acc[u][v] = 0.f;
    for (int ct0 = 0; ct0 < Cc; ct0 += 32) {
        __syncthreads();
        for (int idx = tid; idx < 128 * 32; idx += 256) {
            int r = idx >> 5, cc = idx & 31;
            Abuf[r * 33 + cc] = Q[(size_t)r * rs + ct0 + cc];
            Bbuf[r * 33 + cc] = K[(size_t)r * rs + ct0 + cc];
        }
        __syncthreads();
#pragma unroll 8
        for (int cc = 0; cc < 32; ++cc) {
            float qa[8], ka[8];
#pragma unroll
            for (int u = 0; u < 8; ++u) qa[u] = Abuf[(ti + 16 * u) * 33 + cc];
#pragma unroll
            for (int v = 0; v < 8; ++v) ka[v] = Bbuf[(tj + 16 * v) * 33 + cc];
#pragma unroll
            for (int u = 0; u < 8; ++u)
#pragma unroll
                for (int v = 0; v < 8; ++v) acc[u][v] += qa[u] * ka[v];
        }
    }
    __syncthreads();
#pragma unroll
    for (int u = 0; u < 8; ++u)
#pragma unroll
        for (int v = 0; v < 8; ++v) S[ti + 16 * u][tj + 16 * v] = acc[u][v] * INVTEMP;
    __syncthreads();

    // phase 2: softmax rows (4 waves x 32 rows)
    int wave = tid >> 6, lane = tid & 63;
    for (int rr = 0; rr < 32; ++rr) {
        int row = wave * 32 + rr;
        float s1 = S[row][lane], s2 = S[row][lane + 64];
        float m = fmaxf(s1, s2);
#pragma unroll
        for (int o = 32; o; o >>= 1) m = fmaxf(m, __shfl_xor(m, o));
        float e1 = expf(s1 - m), e2 = expf(s2 - m);
        float sum = e1 + e2;
#pragma unroll
        for (int o = 32; o; o >>= 1) sum += __shfl_xor(sum, o);
        float inv = 1.0f / sum;
        S[row][lane] = e1 * inv;
        S[row][lane + 64] = e2 * inv;
    }
    __syncthreads();

    // phase 3: val = P @ V   (c in two halves of 128)
    for (int ch = 0; ch < 2; ++ch) {
        float acc2[8][8];
#pragma unroll
        for (int u = 0; u < 8; ++u)
#pragma unroll
            for (int w = 0; w < 8; ++w) acc2[u][w] = 0.f;
        for (int jt = 0; jt < 128; jt += 32) {
            __syncthreads();
            for (int idx = tid; idx < 32 * 128; idx += 256) {
                int jj = idx >> 7, cc = idx & 127;
                Abuf[jj * 132 + cc] = V[(size_t)(jt + jj) * rs + ch * 128 + cc];
            }
            __syncthreads();
#pragma unroll 4
            for (int jj = 0; jj < 32; ++jj) {
                float pa[8], va[8];
#pragma unroll
                for (int u = 0; u < 8; ++u) pa[u] = S[ti + 16 * u][jt + jj];
#pragma unroll
                for (int w = 0; w < 8; ++w) va[w] = Abuf[jj * 132 + tj + 16 * w];
#pragma unroll
                for (int u = 0; u < 8; ++u)
#pragma unroll
                    for (int w = 0; w < 8; ++w) acc2[u][w] += pa[u] * va[w];
            }
        }
        float* O = g_val + ((size_t)(b * Gg + g) * BLt) * Cc + ch * 128;
#pragma unroll
        for (int u = 0; u < 8; ++u)
#pragma unroll
            for (int w = 0; w < 8; ++w)
                O[(size_t)(ti + 16 * u) * Cc + tj + 16 * w] = acc2[u][w];
    }
}

// ---------------- K7: opv = perm @ val, written straight into final output layout
__global__ __launch_bounds__(256) void opv_kernel(float* __restrict__ out) {
    // grid: x = B*BL (512) -> (b,l), y = c-half (2)
    __shared__ float Xs[Gg][128];
    __shared__ float ps[Gg][Gg];
    int b = blockIdx.x / BLt, l = blockIdx.x % BLt;
    int c0 = blockIdx.y * 128;
    int tid = threadIdx.x;
    for (int idx = tid; idx < Gg * Gg; idx += 256)
        ps[idx / Gg][idx % Gg] = g_perm[b * Gg * Gg + idx];
    for (int idx = tid; idx < Gg * 128; idx += 256) {
        int g = idx >> 7, c = idx & 127;
        Xs[g][c] = g_val[((size_t)(b * Gg + g) * BLt + l) * Cc + c0 + c];
    }
    __syncthreads();
    int ft = tid >> 5, ct = tid & 31;
    float acc[15][4];
#pragma unroll
    for (int s = 0; s < 15; ++s)
#pragma unroll
        for (int t = 0; t < 4; ++t) acc[s][t] = 0.f;
    for (int g = 0; g < Gg; ++g) {
        float xv0 = Xs[g][ct], xv1 = Xs[g][ct + 32], xv2 = Xs[g][ct + 64], xv3 = Xs[g][ct + 96];
#pragma unroll
        for (int s = 0; s < 15; ++s) {
            float pv = ps[ft + 8 * s][g];
            acc[s][0] += pv * xv0; acc[s][1] += pv * xv1;
            acc[s][2] += pv * xv2; acc[s][3] += pv * xv3;
        }
    }
#pragma unroll
    for (int s = 0; s < 15; ++s) {
        int i = ft + 8 * s;
        int w = i & 7, blk = i >> 3;
        float* o = out + (((size_t)(b * Ww + w) * Nn) + blk * BLt + l) * Cc + c0;
#pragma unroll
        for (int t = 0; t < 4; ++t) o[ct + 32 * t] = acc[s][t];
    }
}

// ---------------- K8: pass-through of last token block: out[b,w,1920+l,c] = v[b,c,1920+l,w]
__global__ __launch_bounds__(256) void vlast_kernel(const float* __restrict__ v,
                                                    float* __restrict__ out) {
    __shared__ float tile[Cc * 9];
    int b = blockIdx.x / BLt, l = blockIdx.x % BLt;
    int n = NB * BLt + l;
    int tid = threadIdx.x;
    for (int idx = tid; idx < Cc * Ww; idx += 256) {
        int c = idx >> 3, w = idx & 7;
        tile[c * 9 + w] = v[(((size_t)b * Cc + c) * Nn + n) * Ww + w];
    }
    __syncthreads();
    for (int idx = tid; idx < Cc * Ww; idx += 256) {
        int w = idx >> 8, c = idx & 255;
        out[(((size_t)b * Ww + w) * Nn + n) * Cc + c] = tile[c * 9 + w];
    }
}

extern "C" void kernel_launch(void* const* d_in, const int* in_sizes, int n_in,
                              void* d_out, int out_size, void* d_ws, size_t ws_size,
                              hipStream_t stream) {
    const float* q = (const float*)d_in[0];
    const float* k = (const float*)d_in[1];
    const float* v = (const float*)d_in[2];
    const float* gumbel = (const float*)d_in[3];
    float* out = (float*)d_out;

    float *p_qt, *p_kt, *p_vt;
    hipGetSymbolAddress((void**)&p_qt, HIP_SYMBOL(g_qt));
    hipGetSymbolAddress((void**)&p_kt, HIP_SYMBOL(g_kt));
    hipGetSymbolAddress((void**)&p_vt, HIP_SYMBOL(g_vt));

    dim3 tgrid(Bn * NB, 16, 4);
    transpose_kernel<<<tgrid, 256, 0, stream>>>(q, p_qt);
    transpose_kernel<<<tgrid, 256, 0, stream>>>(k, p_kt);
    transpose_kernel<<<tgrid, 256, 0, stream>>>(v, p_vt);

    // rows total = 2 * B*BL*G = 122880, 4 rows per block -> 30720 blocks
    mean_kernel<<<30720, 256, 0, stream>>>();
    rmat_kernel<<<(Bn * Gg * Gg + 255) / 256, 256, 0, stream>>>();
    sinkhorn_kernel<<<Bn, 128, 0, stream>>>(gumbel);
    sort_kernel<<<dim3(Bn * BLt, 2, 2), 256, 0, stream>>>();
    attn_kernel<<<Bn * Gg, 256, 0, stream>>>();
    opv_kernel<<<dim3(Bn * BLt, 2), 256, 0, stream>>>(out);
    vlast_kernel<<<Bn * BLt, 256, 0, stream>>>(v, out);
}

// Round 4
// 927.714 us; speedup vs baseline: 1.1744x; 1.1744x over previous
//
#include <hip/hip_runtime.h>
#include <hip/hip_bf16.h>

// Problem constants (from reference)
#define Bn 4
#define Cc 256
#define Nn 2048
#define Ww 8
#define BLt 128     // tokens per block (N/BLOCKS)
#define NB 15       // blocks kept
#define Gg 120      // NB*W
#define TEMP 0.7f
#define INVTEMP (1.0f/0.7f)
#define EPSc 1e-6f

typedef __bf16 bf16_t;
typedef bf16_t bf16x8 __attribute__((ext_vector_type(8)));
typedef float f32x4 __attribute__((ext_vector_type(4)));

// ---------------- workspace in __device__ globals ----------
// head-major layouts:
//  g_qt/g_kt/g_vt: [B][G][BL][C] fp32   (UNsorted, transposed from inputs)
//  g_khi/g_klo:    [B][G][BL][C] bf16   (sorted K, hi/lo split)
//  g_vsb:          [B][G][BL][C] bf16   (sorted V)
//  g_valb:         [B][G][BL][C] bf16   (attention output per head)
__device__ float  g_qt[Bn*Gg*BLt*Cc];
__device__ float  g_kt[Bn*Gg*BLt*Cc];
__device__ float  g_vt[Bn*Gg*BLt*Cc];
__device__ bf16_t g_khi[Bn*Gg*BLt*Cc];
__device__ bf16_t g_klo[Bn*Gg*BLt*Cc];
__device__ bf16_t g_vsb[Bn*Gg*BLt*Cc];
__device__ bf16_t g_valb[Bn*Gg*BLt*Cc];
__device__ float  g_sq[Bn*Gg*BLt];   // [b][g][l] channel means of q
__device__ float  g_sk[Bn*Gg*BLt];
__device__ float  g_R[Bn*Gg*Gg];
__device__ float  g_perm[Bn*Gg*Gg];

// ---------------- K1: transpose  src[b,c,n,w] (n=blk*128+l, blk<15) -> dst[(b*G+g)*BL+l][c], g=blk*8+w
__global__ __launch_bounds__(256) void transpose_kernel(const float* __restrict__ src,
                                                        float* __restrict__ dst) {
    __shared__ float tile[64][65];
    int bblk = blockIdx.x;
    int b = bblk / NB, blk = bblk % NB;
    int lw0 = blockIdx.y * 64;
    int c0  = blockIdx.z * 64;
    int tx = threadIdx.x & 63;
    int ty = threadIdx.x >> 6;   // 0..3
    const float* sbase = src + (size_t)b * Cc * Nn * Ww + (size_t)blk * (BLt * Ww);
#pragma unroll
    for (int j = 0; j < 16; ++j) {
        int cl = ty + j * 4;
        tile[cl][tx] = sbase[(size_t)(c0 + cl) * (Nn * Ww) + lw0 + tx];
    }
    __syncthreads();
#pragma unroll
    for (int j = 0; j < 16; ++j) {
        int lwl = ty + j * 4;
        int lw = lw0 + lwl;
        int l = lw >> 3, w = lw & 7;
        size_t row = ((size_t)b * Gg + blk * Ww + w) * BLt + l;   // head-major
        dst[row * Cc + c0 + tx] = tile[tx][lwl];
    }
}

// ---------------- K2: per-row mean over C (rows enumerate (b,g,l))
__global__ __launch_bounds__(256) void mean_kernel() {
    const long rows = (long)Bn * Gg * BLt;   // 61440
    int wave = threadIdx.x >> 6, lane = threadIdx.x & 63;
    long row = (long)blockIdx.x * 4 + wave;
    const float* src; float* dst; long r;
    if (row < rows) { src = g_qt; dst = g_sq; r = row; }
    else            { src = g_kt; dst = g_sk; r = row - rows; }
    if (r >= rows) return;
    const float* p = src + r * Cc;
    float s = p[lane] + p[lane + 64] + p[lane + 128] + p[lane + 192];
#pragma unroll
    for (int o = 32; o; o >>= 1) s += __shfl_down(s, o);
    if (lane == 0) dst[r] = s * (1.0f / Cc);
}

// ---------------- K3: R[b,i,j] = C^-0.5 * sum_l sq[b,i,l]*sk[b,j,l]  (contiguous dots)
__global__ __launch_bounds__(256) void rmat_kernel() {
    int idx = blockIdx.x * 256 + threadIdx.x;
    if (idx >= Bn * Gg * Gg) return;
    int b = idx / (Gg * Gg);
    int r = idx % (Gg * Gg);
    int i = r / Gg, j = r % Gg;
    const float* pq = g_sq + ((size_t)b * Gg + i) * BLt;
    const float* pk = g_sk + ((size_t)b * Gg + j) * BLt;
    float acc = 0.f;
#pragma unroll 8
    for (int l = 0; l < BLt; ++l) acc += pq[l] * pk[l];
    g_R[idx] = acc * 0.0625f;   // 1/sqrt(256)
}

// ---------------- K4: gumbel-sinkhorn -> perm (fp32)
__global__ void sinkhorn_kernel(const float* __restrict__ gumbel) {
    __shared__ float r[Gg][Gg + 1];
    int b = blockIdx.x, tid = threadIdx.x;   // 128 threads
    for (int idx = tid; idx < Gg * Gg; idx += 128) {
        int i = idx / Gg, j = idx % Gg;
        float x = g_R[b * Gg * Gg + idx];
        x = logf(fmaxf(x, 0.0f) + EPSc);
        r[i][j] = (x + gumbel[b * Gg * Gg + idx]) * INVTEMP;
    }
    for (int it = 0; it < 8; ++it) {
        __syncthreads();
        if (tid < Gg) {
            float m = -1e30f;
            for (int j = 0; j < Gg; ++j) m = fmaxf(m, r[tid][j]);
            float s = 0.f;
            for (int j = 0; j < Gg; ++j) s += expf(r[tid][j] - m);
            float lse = m + logf(s);
            for (int j = 0; j < Gg; ++j) r[tid][j] -= lse;
        }
        __syncthreads();
        if (tid < Gg) {
            float m = -1e30f;
            for (int i = 0; i < Gg; ++i) m = fmaxf(m, r[i][tid]);
            float s = 0.f;
            for (int i = 0; i < Gg; ++i) s += expf(r[i][tid] - m);
            float lse = m + logf(s);
            for (int i = 0; i < Gg; ++i) r[i][tid] -= lse;
        }
    }
    __syncthreads();
    for (int idx = tid; idx < Gg * Gg; idx += 128)
        g_perm[b * Gg * Gg + idx] = expf(r[idx / Gg][idx % Gg]);
}

// ---------------- K5: sort k/v:  Y[f] = sum_g perm[g][f] X[g]  per (b,l,c-half)
// k -> hi/lo bf16 split (feeds precision-critical QK^T); v -> single bf16 (convex-safe)
__global__ __launch_bounds__(256) void sort_kernel() {
    __shared__ float Xs[Gg][128];
    __shared__ float ps[Gg][Gg];
    const float* buf = blockIdx.z ? g_vt : g_kt;
    int b = blockIdx.x / BLt, l = blockIdx.x % BLt;
    int c0 = blockIdx.y * 128;
    int tid = threadIdx.x;
    for (int idx = tid; idx < Gg * Gg; idx += 256)
        ps[idx / Gg][idx % Gg] = g_perm[b * Gg * Gg + idx];
    const float* base = buf + ((size_t)b * Gg * BLt + l) * Cc + c0;
    for (int idx = tid; idx < Gg * 128; idx += 256) {
        int g = idx >> 7, c = idx & 127;
        Xs[g][c] = base[(size_t)g * BLt * Cc + c];
    }
    __syncthreads();
    int ft = tid >> 5;    // 0..7
    int ct = tid & 31;    // 0..31
    float acc[15][4];
#pragma unroll
    for (int s = 0; s < 15; ++s)
#pragma unroll
        for (int t = 0; t < 4; ++t) acc[s][t] = 0.f;
    for (int g = 0; g < Gg; ++g) {
        float xv0 = Xs[g][ct], xv1 = Xs[g][ct + 32], xv2 = Xs[g][ct + 64], xv3 = Xs[g][ct + 96];
#pragma unroll
        for (int s = 0; s < 15; ++s) {
            float pv = ps[g][ft + 8 * s];
            acc[s][0] += pv * xv0; acc[s][1] += pv * xv1;
            acc[s][2] += pv * xv2; acc[s][3] += pv * xv3;
        }
    }
#pragma unroll
    for (int s = 0; s < 15; ++s) {
        int f = ft + 8 * s;
        size_t rbase = ((size_t)(b * Gg + f) * BLt + l) * Cc + c0 + ct;
        if (blockIdx.z == 0) {
#pragma unroll
            for (int t = 0; t < 4; ++t) {
                float x = acc[s][t];
                bf16_t h = (bf16_t)x;
                bf16_t lo = (bf16_t)(x - (float)h);
                g_khi[rbase + 32 * t] = h;
                g_klo[rbase + 32 * t] = lo;
            }
        } else {
#pragma unroll
            for (int t = 0; t < 4; ++t) g_vsb[rbase + 32 * t] = (bf16_t)acc[s][t];
        }
    }
}

// ---------------- K6: MFMA attention per head (b,g): S=QK^T/T, softmax(in-reg), val=PV
__global__ __launch_bounds__(256, 2) void attn_mfma_kernel() {
    union SM {
        struct { bf16_t Qh[128][56], Ql[128][56], Kh[128][56], Kl[128][56]; } p1; // 57344 B
        struct { bf16_t P[128][136]; unsigned int VT[128][36]; bf16_t VS[4][16][136]; } p3; // 70656 B
    };
    __shared__ SM sm;
    const int tid = threadIdx.x;
    const int lane = tid & 63, w = tid >> 6;
    const int r16 = lane & 15, q4 = lane >> 4;
    const int hb = blockIdx.x;
    const int b = hb / Gg, g = hb % Gg;
    const size_t hbase = (size_t)(b * Gg + g) * BLt * Cc;
    const float*  Q  = g_qt + hbase;
    const unsigned short* KH = (const unsigned short*)(g_khi + hbase);
    const unsigned short* KL = (const unsigned short*)(g_klo + hbase);
    const unsigned short* V  = (const unsigned short*)(g_vsb + hbase);
    bf16_t* OUT = g_valb + hbase;

    // ---- phase 1: S = Q K^T with hi/lo split (3 MFMAs), acc in fp32
    f32x4 acc[2][8];
#pragma unroll
    for (int mt = 0; mt < 2; ++mt)
#pragma unroll
        for (int nt = 0; nt < 8; ++nt) acc[mt][nt] = (f32x4)0.f;

    const int si = tid >> 1, sc = (tid & 1) * 16;   // staging: row, col-chunk
    for (int ks = 0; ks < 8; ++ks) {
        __syncthreads();
        {   // stage Q (fp32 -> hi/lo) and K (pre-split bf16) c-chunk of 32
            union { float4 v4[4]; float f[16]; } u;
            const float4* qp = (const float4*)(Q + (size_t)si * Cc + ks * 32 + sc);
#pragma unroll
            for (int t = 0; t < 4; ++t) u.v4[t] = qp[t];
            bf16_t hbuf[16], lbuf[16];
#pragma unroll
            for (int t = 0; t < 16; ++t) {
                float x = u.f[t];
                bf16_t h = (bf16_t)x;
                hbuf[t] = h;
                lbuf[t] = (bf16_t)(x - (float)h);
            }
            ((uint4*)&sm.p1.Qh[si][sc])[0] = ((uint4*)hbuf)[0];
            ((uint4*)&sm.p1.Qh[si][sc + 8])[0] = ((uint4*)hbuf)[1];
            ((uint4*)&sm.p1.Ql[si][sc])[0] = ((uint4*)lbuf)[0];
            ((uint4*)&sm.p1.Ql[si][sc + 8])[0] = ((uint4*)lbuf)[1];
            const uint4* khp = (const uint4*)(KH + (size_t)si * Cc + ks * 32 + sc);
            const uint4* klp = (const uint4*)(KL + (size_t)si * Cc + ks * 32 + sc);
            ((uint4*)&sm.p1.Kh[si][sc])[0] = khp[0];
            ((uint4*)&sm.p1.Kh[si][sc + 8])[0] = khp[1];
            ((uint4*)&sm.p1.Kl[si][sc])[0] = klp[0];
            ((uint4*)&sm.p1.Kl[si][sc + 8])[0] = klp[1];
        }
        __syncthreads();
        bf16x8 ah[2], al[2];
#pragma unroll
        for (int mt = 0; mt < 2; ++mt) {
            ah[mt] = *(const bf16x8*)&sm.p1.Qh[w * 32 + mt * 16 + r16][q4 * 8];
            al[mt] = *(const bf16x8*)&sm.p1.Ql[w * 32 + mt * 16 + r16][q4 * 8];
        }
#pragma unroll
        for (int nt = 0; nt < 8; ++nt) {
            bf16x8 bh = *(const bf16x8*)&sm.p1.Kh[nt * 16 + r16][q4 * 8];
            bf16x8 bl = *(const bf16x8*)&sm.p1.Kl[nt * 16 + r16][q4 * 8];
#pragma unroll
            for (int mt = 0; mt < 2; ++mt) {
                acc[mt][nt] = __builtin_amdgcn_mfma_f32_16x16x32_bf16(ah[mt], bh, acc[mt][nt], 0, 0, 0);
                acc[mt][nt] = __builtin_amdgcn_mfma_f32_16x16x32_bf16(ah[mt], bl, acc[mt][nt], 0, 0, 0);
                acc[mt][nt] = __builtin_amdgcn_mfma_f32_16x16x32_bf16(al[mt], bh, acc[mt][nt], 0, 0, 0);
            }
        }
    }
    __syncthreads();   // all phase-1 LDS reads done; safe to overwrite with P

    // ---- phase 2: softmax over j (in-register; D rows = q4*4+r, cols = r16+16nt)
#pragma unroll
    for (int mt = 0; mt < 2; ++mt) {
        float p[8][4];
#pragma unroll
        for (int r = 0; r < 4; ++r) {
            float m = acc[mt][0][r];
#pragma unroll
            for (int nt = 1; nt < 8; ++nt) m = fmaxf(m, acc[mt][nt][r]);
#pragma unroll
            for (int msk = 1; msk < 16; msk <<= 1) m = fmaxf(m, __shfl_xor(m, msk));
            float s = 0.f;
#pragma unroll
            for (int nt = 0; nt < 8; ++nt) {
                float e = expf((acc[mt][nt][r] - m) * INVTEMP);
                p[nt][r] = e; s += e;
            }
#pragma unroll
            for (int msk = 1; msk < 16; msk <<= 1) s += __shfl_xor(s, msk);
            float inv = 1.0f / s;
#pragma unroll
            for (int nt = 0; nt < 8; ++nt) p[nt][r] *= inv;
        }
#pragma unroll
        for (int nt = 0; nt < 8; ++nt)
#pragma unroll
            for (int r = 0; r < 4; ++r)
                sm.p3.P[w * 32 + mt * 16 + q4 * 4 + r][r16 + nt * 16] = (bf16_t)p[nt][r];
    }

    // ---- phase 3: val = P V per c-half; V transpose-staged as packed u32 pairs
    for (int ch = 0; ch < 2; ++ch) {
        f32x4 acc2[2][8];
#pragma unroll
        for (int mt = 0; mt < 2; ++mt)
#pragma unroll
            for (int nt = 0; nt < 8; ++nt) acc2[mt][nt] = (f32x4)0.f;
        for (int jh = 0; jh < 2; ++jh) {
            __syncthreads();
            {   // stage VT[c][j/2] = (V[j][c], V[j+1][c])
                int c = tid & 127, jp = tid >> 7;
#pragma unroll
                for (int t = 0; t < 16; ++t) {
                    int j = jh * 64 + jp * 32 + t * 2;
                    unsigned lo = V[(size_t)j * Cc + ch * 128 + c];
                    unsigned hi = V[(size_t)(j + 1) * Cc + ch * 128 + c];
                    sm.p3.VT[c][jp * 16 + t] = lo | (hi << 16);
                }
            }
            __syncthreads();
#pragma unroll
            for (int ks = 0; ks < 2; ++ks) {
                bf16x8 pa[2];
#pragma unroll
                for (int mt = 0; mt < 2; ++mt)
                    pa[mt] = *(const bf16x8*)&sm.p3.P[w * 32 + mt * 16 + r16][jh * 64 + ks * 32 + q4 * 8];
#pragma unroll
                for (int nt = 0; nt < 8; ++nt) {
                    bf16x8 vv = *(const bf16x8*)&sm.p3.VT[nt * 16 + r16][ks * 16 + q4 * 4];
#pragma unroll
                    for (int mt = 0; mt < 2; ++mt)
                        acc2[mt][nt] = __builtin_amdgcn_mfma_f32_16x16x32_bf16(pa[mt], vv, acc2[mt][nt], 0, 0, 0);
                }
            }
        }
        // write val via LDS roundtrip for coalesced bf16 stores
#pragma unroll
        for (int mt = 0; mt < 2; ++mt) {
            __syncthreads();
#pragma unroll
            for (int nt = 0; nt < 8; ++nt)
#pragma unroll
                for (int r = 0; r < 4; ++r)
                    sm.p3.VS[w][q4 * 4 + r][r16 + nt * 16] = (bf16_t)acc2[mt][nt][r];
            __syncthreads();
            int row = lane >> 2, cq = (lane & 3) * 32;
            int i = w * 32 + mt * 16 + row;
            bf16_t* op = OUT + (size_t)i * Cc + ch * 128 + cq;
#pragma unroll
            for (int t = 0; t < 4; ++t)
                ((uint4*)op)[t] = *(const uint4*)&sm.p3.VS[w][row][cq + t * 8];
        }
    }
}

// ---------------- K7: opv = perm @ val -> final output layout (fp32 vector)
__global__ __launch_bounds__(256) void opv_kernel(float* __restrict__ out) {
    __shared__ float Xs[Gg][128];
    __shared__ float ps[Gg][Gg];
    int b = blockIdx.x / BLt, l = blockIdx.x % BLt;
    int c0 = blockIdx.y * 128;
    int tid = threadIdx.x;
    for (int idx = tid; idx < Gg * Gg; idx += 256)
        ps[idx / Gg][idx % Gg] = g_perm[b * Gg * Gg + idx];
    for (int idx = tid; idx < Gg * 128; idx += 256) {
        int g = idx >> 7, c = idx & 127;
        Xs[g][c] = (float)g_valb[((size_t)(b * Gg + g) * BLt + l) * Cc + c0 + c];
    }
    __syncthreads();
    int ft = tid >> 5, ct = tid & 31;
    float acc[15][4];
#pragma unroll
    for (int s = 0; s < 15; ++s)
#pragma unroll
        for (int t = 0; t < 4; ++t) acc[s][t] = 0.f;
    for (int g = 0; g < Gg; ++g) {
        float xv0 = Xs[g][ct], xv1 = Xs[g][ct + 32], xv2 = Xs[g][ct + 64], xv3 = Xs[g][ct + 96];
#pragma unroll
        for (int s = 0; s < 15; ++s) {
            float pv = ps[ft + 8 * s][g];
            acc[s][0] += pv * xv0; acc[s][1] += pv * xv1;
            acc[s][2] += pv * xv2; acc[s][3] += pv * xv3;
        }
    }
#pragma unroll
    for (int s = 0; s < 15; ++s) {
        int i = ft + 8 * s;
        int w = i & 7, blk = i >> 3;
        float* o = out + (((size_t)(b * Ww + w) * Nn) + blk * BLt + l) * Cc + c0;
#pragma unroll
        for (int t = 0; t < 4; ++t) o[ct + 32 * t] = acc[s][t];
    }
}

// ---------------- K8: pass-through of last token block
__global__ __launch_bounds__(256) void vlast_kernel(const float* __restrict__ v,
                                                    float* __restrict__ out) {
    __shared__ float tile[Cc * 9];
    int b = blockIdx.x / BLt, l = blockIdx.x % BLt;
    int n = NB * BLt + l;
    int tid = threadIdx.x;
    for (int idx = tid; idx < Cc * Ww; idx += 256) {
        int c = idx >> 3, w = idx & 7;
        tile[c * 9 + w] = v[(((size_t)b * Cc + c) * Nn + n) * Ww + w];
    }
    __syncthreads();
    for (int idx = tid; idx < Cc * Ww; idx += 256) {
        int w = idx >> 8, c = idx & 255;
        out[(((size_t)b * Ww + w) * Nn + n) * Cc + c] = tile[c * 9 + w];
    }
}

extern "C" void kernel_launch(void* const* d_in, const int* in_sizes, int n_in,
                              void* d_out, int out_size, void* d_ws, size_t ws_size,
                              hipStream_t stream) {
    const float* q = (const float*)d_in[0];
    const float* k = (const float*)d_in[1];
    const float* v = (const float*)d_in[2];
    const float* gumbel = (const float*)d_in[3];
    float* out = (float*)d_out;

    float *p_qt, *p_kt, *p_vt;
    hipGetSymbolAddress((void**)&p_qt, HIP_SYMBOL(g_qt));
    hipGetSymbolAddress((void**)&p_kt, HIP_SYMBOL(g_kt));
    hipGetSymbolAddress((void**)&p_vt, HIP_SYMBOL(g_vt));

    dim3 tgrid(Bn * NB, 16, 4);
    transpose_kernel<<<tgrid, 256, 0, stream>>>(q, p_qt);
    transpose_kernel<<<tgrid, 256, 0, stream>>>(k, p_kt);
    transpose_kernel<<<tgrid, 256, 0, stream>>>(v, p_vt);

    mean_kernel<<<30720, 256, 0, stream>>>();
    rmat_kernel<<<(Bn * Gg * Gg + 255) / 256, 256, 0, stream>>>();
    sinkhorn_kernel<<<Bn, 128, 0, stream>>>(gumbel);
    sort_kernel<<<dim3(Bn * BLt, 2, 2), 256, 0, stream>>>();
    attn_mfma_kernel<<<Bn * Gg, 256, 0, stream>>>();
    opv_kernel<<<dim3(Bn * BLt, 2), 256, 0, stream>>>(out);
    vlast_kernel<<<Bn * BLt, 256, 0, stream>>>(v, out);
}

// Round 5
// 824.839 us; speedup vs baseline: 1.3208x; 1.1247x over previous
//
#include <hip/hip_runtime.h>
#include <hip/hip_bf16.h>

// Problem constants (from reference)
#define Bn 4
#define Cc 256
#define Nn 2048
#define Ww 8
#define BLt 128     // tokens per block (N/BLOCKS)
#define NB 15       // blocks kept
#define Gg 120      // NB*W
#define TEMP 0.7f
#define INVTEMP (1.0f/0.7f)
#define EPSc 1e-6f

typedef __bf16 bf16_t;
typedef bf16_t bf16x8 __attribute__((ext_vector_type(8)));
typedef float f32x4 __attribute__((ext_vector_type(4)));

// ---------------- workspace in __device__ globals ----------
// head-major layouts:
//  g_qt/g_kt/g_vt: [B][G][BL][C] fp32   (UNsorted, transposed from inputs)
//  g_khi/g_klo:    [B][G][BL][C] bf16   (sorted K, hi/lo split)
//  g_vsb:          [B][G][BL][C] bf16   (sorted V)
//  g_valb:         [B][G][BL][C] bf16   (attention output per head)
__device__ float  g_qt[Bn*Gg*BLt*Cc];
__device__ float  g_kt[Bn*Gg*BLt*Cc];
__device__ float  g_vt[Bn*Gg*BLt*Cc];
__device__ bf16_t g_khi[Bn*Gg*BLt*Cc];
__device__ bf16_t g_klo[Bn*Gg*BLt*Cc];
__device__ bf16_t g_vsb[Bn*Gg*BLt*Cc];
__device__ bf16_t g_valb[Bn*Gg*BLt*Cc];
__device__ float  g_sq[Bn*Gg*BLt];   // [b][g][l] channel means of q
__device__ float  g_sk[Bn*Gg*BLt];
__device__ float  g_R[Bn*Gg*Gg];
__device__ float  g_perm[Bn*Gg*Gg];

// ---------------- K1: transpose  src[b,c,n,w] (n=blk*128+l, blk<15) -> dst[(b*G+g)*BL+l][c], g=blk*8+w
__global__ __launch_bounds__(256) void transpose_kernel(const float* __restrict__ src,
                                                        float* __restrict__ dst) {
    __shared__ float tile[64][65];
    int bblk = blockIdx.x;
    int b = bblk / NB, blk = bblk % NB;
    int lw0 = blockIdx.y * 64;
    int c0  = blockIdx.z * 64;
    int tx = threadIdx.x & 63;
    int ty = threadIdx.x >> 6;   // 0..3
    const float* sbase = src + (size_t)b * Cc * Nn * Ww + (size_t)blk * (BLt * Ww);
#pragma unroll
    for (int j = 0; j < 16; ++j) {
        int cl = ty + j * 4;
        tile[cl][tx] = sbase[(size_t)(c0 + cl) * (Nn * Ww) + lw0 + tx];
    }
    __syncthreads();
#pragma unroll
    for (int j = 0; j < 16; ++j) {
        int lwl = ty + j * 4;
        int lw = lw0 + lwl;
        int l = lw >> 3, w = lw & 7;
        size_t row = ((size_t)b * Gg + blk * Ww + w) * BLt + l;   // head-major
        dst[row * Cc + c0 + tx] = tile[tx][lwl];
    }
}

// ---------------- K2: per-row mean over C (rows enumerate (b,g,l))
__global__ __launch_bounds__(256) void mean_kernel() {
    const long rows = (long)Bn * Gg * BLt;   // 61440
    int wave = threadIdx.x >> 6, lane = threadIdx.x & 63;
    long row = (long)blockIdx.x * 4 + wave;
    const float* src; float* dst; long r;
    if (row < rows) { src = g_qt; dst = g_sq; r = row; }
    else            { src = g_kt; dst = g_sk; r = row - rows; }
    if (r >= rows) return;
    const float* p = src + r * Cc;
    float s = p[lane] + p[lane + 64] + p[lane + 128] + p[lane + 192];
#pragma unroll
    for (int o = 32; o; o >>= 1) s += __shfl_down(s, o);
    if (lane == 0) dst[r] = s * (1.0f / Cc);
}

// ---------------- K3: R[b,i,j] = C^-0.5 * sum_l sq[b,i,l]*sk[b,j,l]  (contiguous dots)
__global__ __launch_bounds__(256) void rmat_kernel() {
    int idx = blockIdx.x * 256 + threadIdx.x;
    if (idx >= Bn * Gg * Gg) return;
    int b = idx / (Gg * Gg);
    int r = idx % (Gg * Gg);
    int i = r / Gg, j = r % Gg;
    const float* pq = g_sq + ((size_t)b * Gg + i) * BLt;
    const float* pk = g_sk + ((size_t)b * Gg + j) * BLt;
    float acc = 0.f;
#pragma unroll 8
    for (int l = 0; l < BLt; ++l) acc += pq[l] * pk[l];
    g_R[idx] = acc * 0.0625f;   // 1/sqrt(256)
}

// ---------------- K4: gumbel-sinkhorn -> perm (fp32, wave-parallel LSE)
// one block per batch; 512 threads = 8 waves; wave owns a row (col), lane l holds
// elements l and l+64 (G=120 <= 128); butterfly shfl reduce.
__global__ __launch_bounds__(512) void sinkhorn_kernel(const float* __restrict__ gumbel) {
    __shared__ float r[Gg][Gg + 1];
    const int b = blockIdx.x, tid = threadIdx.x;
    const int wave = tid >> 6, lane = tid & 63;
    const bool hi = (lane < Gg - 64);   // lane+64 < 120

    for (int idx = tid; idx < Gg * Gg; idx += 512) {
        int i = idx / Gg, j = idx % Gg;
        float x = g_R[b * Gg * Gg + idx];
        x = logf(fmaxf(x, 0.0f) + EPSc);
        r[i][j] = (x + gumbel[b * Gg * Gg + idx]) * INVTEMP;
    }
    for (int it = 0; it < 8; ++it) {
        __syncthreads();
        // row LSE (over j)
        for (int i = wave; i < Gg; i += 8) {
            float a0 = r[i][lane];
            float a1 = hi ? r[i][lane + 64] : -1e30f;
            float m = fmaxf(a0, a1);
#pragma unroll
            for (int o = 32; o; o >>= 1) m = fmaxf(m, __shfl_xor(m, o));
            float s = expf(a0 - m) + (hi ? expf(a1 - m) : 0.f);
#pragma unroll
            for (int o = 32; o; o >>= 1) s += __shfl_xor(s, o);
            float lse = m + logf(s);
            r[i][lane] = a0 - lse;
            if (hi) r[i][lane + 64] = a1 - lse;
        }
        __syncthreads();
        // col LSE (over i)
        for (int j = wave; j < Gg; j += 8) {
            float a0 = r[lane][j];
            float a1 = hi ? r[lane + 64][j] : -1e30f;
            float m = fmaxf(a0, a1);
#pragma unroll
            for (int o = 32; o; o >>= 1) m = fmaxf(m, __shfl_xor(m, o));
            float s = expf(a0 - m) + (hi ? expf(a1 - m) : 0.f);
#pragma unroll
            for (int o = 32; o; o >>= 1) s += __shfl_xor(s, o);
            float lse = m + logf(s);
            r[lane][j] = a0 - lse;
            if (hi) r[lane + 64][j] = a1 - lse;
        }
    }
    __syncthreads();
    for (int idx = tid; idx < Gg * Gg; idx += 512)
        g_perm[b * Gg * Gg + idx] = expf(r[idx / Gg][idx % Gg]);
}

// ---------------- K5: sort k/v:  Y[f] = sum_g perm[g][f] X[g]  per (b,l,c-half)
// k -> hi/lo bf16 split (feeds precision-critical QK^T); v -> single bf16 (convex-safe)
__global__ __launch_bounds__(256) void sort_kernel() {
    __shared__ float Xs[Gg][128];
    __shared__ float ps[Gg][Gg];
    const float* buf = blockIdx.z ? g_vt : g_kt;
    int b = blockIdx.x / BLt, l = blockIdx.x % BLt;
    int c0 = blockIdx.y * 128;
    int tid = threadIdx.x;
    for (int idx = tid; idx < Gg * Gg; idx += 256)
        ps[idx / Gg][idx % Gg] = g_perm[b * Gg * Gg + idx];
    const float* base = buf + ((size_t)b * Gg * BLt + l) * Cc + c0;
    for (int idx = tid; idx < Gg * 128; idx += 256) {
        int g = idx >> 7, c = idx & 127;
        Xs[g][c] = base[(size_t)g * BLt * Cc + c];
    }
    __syncthreads();
    int ft = tid >> 5;    // 0..7
    int ct = tid & 31;    // 0..31
    float acc[15][4];
#pragma unroll
    for (int s = 0; s < 15; ++s)
#pragma unroll
        for (int t = 0; t < 4; ++t) acc[s][t] = 0.f;
    for (int g = 0; g < Gg; ++g) {
        float xv0 = Xs[g][ct], xv1 = Xs[g][ct + 32], xv2 = Xs[g][ct + 64], xv3 = Xs[g][ct + 96];
#pragma unroll
        for (int s = 0; s < 15; ++s) {
            float pv = ps[g][ft + 8 * s];
            acc[s][0] += pv * xv0; acc[s][1] += pv * xv1;
            acc[s][2] += pv * xv2; acc[s][3] += pv * xv3;
        }
    }
#pragma unroll
    for (int s = 0; s < 15; ++s) {
        int f = ft + 8 * s;
        size_t rbase = ((size_t)(b * Gg + f) * BLt + l) * Cc + c0 + ct;
        if (blockIdx.z == 0) {
#pragma unroll
            for (int t = 0; t < 4; ++t) {
                float x = acc[s][t];
                bf16_t h = (bf16_t)x;
                bf16_t lo = (bf16_t)(x - (float)h);
                g_khi[rbase + 32 * t] = h;
                g_klo[rbase + 32 * t] = lo;
            }
        } else {
#pragma unroll
            for (int t = 0; t < 4; ++t) g_vsb[rbase + 32 * t] = (bf16_t)acc[s][t];
        }
    }
}

// ---------------- K6: MFMA attention per head (b,g): S=QK^T/T, softmax(in-reg), val=PV
__global__ __launch_bounds__(256, 2) void attn_mfma_kernel() {
    union SM {
        struct { bf16_t Qh[128][56], Ql[128][56], Kh[128][56], Kl[128][56]; } p1; // 57344 B
        struct { bf16_t P[128][136]; unsigned int VT[128][36]; bf16_t VS[4][16][136]; } p3; // 70656 B
    };
    __shared__ SM sm;
    const int tid = threadIdx.x;
    const int lane = tid & 63, w = tid >> 6;
    const int r16 = lane & 15, q4 = lane >> 4;
    const int hb = blockIdx.x;
    const int b = hb / Gg, g = hb % Gg;
    const size_t hbase = (size_t)(b * Gg + g) * BLt * Cc;
    const float*  Q  = g_qt + hbase;
    const unsigned short* KH = (const unsigned short*)(g_khi + hbase);
    const unsigned short* KL = (const unsigned short*)(g_klo + hbase);
    const unsigned short* V  = (const unsigned short*)(g_vsb + hbase);
    bf16_t* OUT = g_valb + hbase;

    // ---- phase 1: S = Q K^T with hi/lo split (3 MFMAs), acc in fp32
    f32x4 acc[2][8];
#pragma unroll
    for (int mt = 0; mt < 2; ++mt)
#pragma unroll
        for (int nt = 0; nt < 8; ++nt) acc[mt][nt] = (f32x4)0.f;

    const int si = tid >> 1, sc = (tid & 1) * 16;   // staging: row, col-chunk
    for (int ks = 0; ks < 8; ++ks) {
        __syncthreads();
        {   // stage Q (fp32 -> hi/lo) and K (pre-split bf16) c-chunk of 32
            union { float4 v4[4]; float f[16]; } u;
            const float4* qp = (const float4*)(Q + (size_t)si * Cc + ks * 32 + sc);
#pragma unroll
            for (int t = 0; t < 4; ++t) u.v4[t] = qp[t];
            bf16_t hbuf[16], lbuf[16];
#pragma unroll
            for (int t = 0; t < 16; ++t) {
                float x = u.f[t];
                bf16_t h = (bf16_t)x;
                hbuf[t] = h;
                lbuf[t] = (bf16_t)(x - (float)h);
            }
            ((uint4*)&sm.p1.Qh[si][sc])[0] = ((uint4*)hbuf)[0];
            ((uint4*)&sm.p1.Qh[si][sc + 8])[0] = ((uint4*)hbuf)[1];
            ((uint4*)&sm.p1.Ql[si][sc])[0] = ((uint4*)lbuf)[0];
            ((uint4*)&sm.p1.Ql[si][sc + 8])[0] = ((uint4*)lbuf)[1];
            const uint4* khp = (const uint4*)(KH + (size_t)si * Cc + ks * 32 + sc);
            const uint4* klp = (const uint4*)(KL + (size_t)si * Cc + ks * 32 + sc);
            ((uint4*)&sm.p1.Kh[si][sc])[0] = khp[0];
            ((uint4*)&sm.p1.Kh[si][sc + 8])[0] = khp[1];
            ((uint4*)&sm.p1.Kl[si][sc])[0] = klp[0];
            ((uint4*)&sm.p1.Kl[si][sc + 8])[0] = klp[1];
        }
        __syncthreads();
        bf16x8 ah[2], al[2];
#pragma unroll
        for (int mt = 0; mt < 2; ++mt) {
            ah[mt] = *(const bf16x8*)&sm.p1.Qh[w * 32 + mt * 16 + r16][q4 * 8];
            al[mt] = *(const bf16x8*)&sm.p1.Ql[w * 32 + mt * 16 + r16][q4 * 8];
        }
#pragma unroll
        for (int nt = 0; nt < 8; ++nt) {
            bf16x8 bh = *(const bf16x8*)&sm.p1.Kh[nt * 16 + r16][q4 * 8];
            bf16x8 bl = *(const bf16x8*)&sm.p1.Kl[nt * 16 + r16][q4 * 8];
#pragma unroll
            for (int mt = 0; mt < 2; ++mt) {
                acc[mt][nt] = __builtin_amdgcn_mfma_f32_16x16x32_bf16(ah[mt], bh, acc[mt][nt], 0, 0, 0);
                acc[mt][nt] = __builtin_amdgcn_mfma_f32_16x16x32_bf16(ah[mt], bl, acc[mt][nt], 0, 0, 0);
                acc[mt][nt] = __builtin_amdgcn_mfma_f32_16x16x32_bf16(al[mt], bh, acc[mt][nt], 0, 0, 0);
            }
        }
    }
    __syncthreads();   // all phase-1 LDS reads done; safe to overwrite with P

    // ---- phase 2: softmax over j (in-register; D rows = q4*4+r, cols = r16+16nt)
#pragma unroll
    for (int mt = 0; mt < 2; ++mt) {
        float p[8][4];
#pragma unroll
        for (int r = 0; r < 4; ++r) {
            float m = acc[mt][0][r];
#pragma unroll
            for (int nt = 1; nt < 8; ++nt) m = fmaxf(m, acc[mt][nt][r]);
#pragma unroll
            for (int msk = 1; msk < 16; msk <<= 1) m = fmaxf(m, __shfl_xor(m, msk));
            float s = 0.f;
#pragma unroll
            for (int nt = 0; nt < 8; ++nt) {
                float e = expf((acc[mt][nt][r] - m) * INVTEMP);
                p[nt][r] = e; s += e;
            }
#pragma unroll
            for (int msk = 1; msk < 16; msk <<= 1) s += __shfl_xor(s, msk);
            float inv = 1.0f / s;
#pragma unroll
            for (int nt = 0; nt < 8; ++nt) p[nt][r] *= inv;
        }
#pragma unroll
        for (int nt = 0; nt < 8; ++nt)
#pragma unroll
            for (int r = 0; r < 4; ++r)
                sm.p3.P[w * 32 + mt * 16 + q4 * 4 + r][r16 + nt * 16] = (bf16_t)p[nt][r];
    }

    // ---- phase 3: val = P V per c-half; V transpose-staged as packed u32 pairs
    for (int ch = 0; ch < 2; ++ch) {
        f32x4 acc2[2][8];
#pragma unroll
        for (int mt = 0; mt < 2; ++mt)
#pragma unroll
            for (int nt = 0; nt < 8; ++nt) acc2[mt][nt] = (f32x4)0.f;
        for (int jh = 0; jh < 2; ++jh) {
            __syncthreads();
            {   // stage VT[c][j/2] = (V[j][c], V[j+1][c])
                int c = tid & 127, jp = tid >> 7;
#pragma unroll
                for (int t = 0; t < 16; ++t) {
                    int j = jh * 64 + jp * 32 + t * 2;
                    unsigned lo = V[(size_t)j * Cc + ch * 128 + c];
                    unsigned hi = V[(size_t)(j + 1) * Cc + ch * 128 + c];
                    sm.p3.VT[c][jp * 16 + t] = lo | (hi << 16);
                }
            }
            __syncthreads();
#pragma unroll
            for (int ks = 0; ks < 2; ++ks) {
                bf16x8 pa[2];
#pragma unroll
                for (int mt = 0; mt < 2; ++mt)
                    pa[mt] = *(const bf16x8*)&sm.p3.P[w * 32 + mt * 16 + r16][jh * 64 + ks * 32 + q4 * 8];
#pragma unroll
                for (int nt = 0; nt < 8; ++nt) {
                    bf16x8 vv = *(const bf16x8*)&sm.p3.VT[nt * 16 + r16][ks * 16 + q4 * 4];
#pragma unroll
                    for (int mt = 0; mt < 2; ++mt)
                        acc2[mt][nt] = __builtin_amdgcn_mfma_f32_16x16x32_bf16(pa[mt], vv, acc2[mt][nt], 0, 0, 0);
                }
            }
        }
        // write val via LDS roundtrip for coalesced bf16 stores
#pragma unroll
        for (int mt = 0; mt < 2; ++mt) {
            __syncthreads();
#pragma unroll
            for (int nt = 0; nt < 8; ++nt)
#pragma unroll
                for (int r = 0; r < 4; ++r)
                    sm.p3.VS[w][q4 * 4 + r][r16 + nt * 16] = (bf16_t)acc2[mt][nt][r];
            __syncthreads();
            int row = lane >> 2, cq = (lane & 3) * 32;
            int i = w * 32 + mt * 16 + row;
            bf16_t* op = OUT + (size_t)i * Cc + ch * 128 + cq;
#pragma unroll
            for (int t = 0; t < 4; ++t)
                ((uint4*)op)[t] = *(const uint4*)&sm.p3.VS[w][row][cq + t * 8];
        }
    }
}

// ---------------- K7: opv = perm @ val -> final output layout (fp32 vector)
__global__ __launch_bounds__(256) void opv_kernel(float* __restrict__ out) {
    __shared__ float Xs[Gg][128];
    __shared__ float ps[Gg][Gg];
    int b = blockIdx.x / BLt, l = blockIdx.x % BLt;
    int c0 = blockIdx.y * 128;
    int tid = threadIdx.x;
    for (int idx = tid; idx < Gg * Gg; idx += 256)
        ps[idx / Gg][idx % Gg] = g_perm[b * Gg * Gg + idx];
    for (int idx = tid; idx < Gg * 128; idx += 256) {
        int g = idx >> 7, c = idx & 127;
        Xs[g][c] = (float)g_valb[((size_t)(b * Gg + g) * BLt + l) * Cc + c0 + c];
    }
    __syncthreads();
    int ft = tid >> 5, ct = tid & 31;
    float acc[15][4];
#pragma unroll
    for (int s = 0; s < 15; ++s)
#pragma unroll
        for (int t = 0; t < 4; ++t) acc[s][t] = 0.f;
    for (int g = 0; g < Gg; ++g) {
        float xv0 = Xs[g][ct], xv1 = Xs[g][ct + 32], xv2 = Xs[g][ct + 64], xv3 = Xs[g][ct + 96];
#pragma unroll
        for (int s = 0; s < 15; ++s) {
            float pv = ps[ft + 8 * s][g];
            acc[s][0] += pv * xv0; acc[s][1] += pv * xv1;
            acc[s][2] += pv * xv2; acc[s][3] += pv * xv3;
        }
    }
#pragma unroll
    for (int s = 0; s < 15; ++s) {
        int i = ft + 8 * s;
        int w = i & 7, blk = i >> 3;
        float* o = out + (((size_t)(b * Ww + w) * Nn) + blk * BLt + l) * Cc + c0;
#pragma unroll
        for (int t = 0; t < 4; ++t) o[ct + 32 * t] = acc[s][t];
    }
}

// ---------------- K8: pass-through of last token block
__global__ __launch_bounds__(256) void vlast_kernel(const float* __restrict__ v,
                                                    float* __restrict__ out) {
    __shared__ float tile[Cc * 9];
    int b = blockIdx.x / BLt, l = blockIdx.x % BLt;
    int n = NB * BLt + l;
    int tid = threadIdx.x;
    for (int idx = tid; idx < Cc * Ww; idx += 256) {
        int c = idx >> 3, w = idx & 7;
        tile[c * 9 + w] = v[(((size_t)b * Cc + c) * Nn + n) * Ww + w];
    }
    __syncthreads();
    for (int idx = tid; idx < Cc * Ww; idx += 256) {
        int w = idx >> 8, c = idx & 255;
        out[(((size_t)b * Ww + w) * Nn + n) * Cc + c] = tile[c * 9 + w];
    }
}

extern "C" void kernel_launch(void* const* d_in, const int* in_sizes, int n_in,
                              void* d_out, int out_size, void* d_ws, size_t ws_size,
                              hipStream_t stream) {
    const float* q = (const float*)d_in[0];
    const float* k = (const float*)d_in[1];
    const float* v = (const float*)d_in[2];
    const float* gumbel = (const float*)d_in[3];
    float* out = (float*)d_out;

    float *p_qt, *p_kt, *p_vt;
    hipGetSymbolAddress((void**)&p_qt, HIP_SYMBOL(g_qt));
    hipGetSymbolAddress((void**)&p_kt, HIP_SYMBOL(g_kt));
    hipGetSymbolAddress((void**)&p_vt, HIP_SYMBOL(g_vt));

    dim3 tgrid(Bn * NB, 16, 4);
    transpose_kernel<<<tgrid, 256, 0, stream>>>(q, p_qt);
    transpose_kernel<<<tgrid, 256, 0, stream>>>(k, p_kt);
    transpose_kernel<<<tgrid, 256, 0, stream>>>(v, p_vt);

    mean_kernel<<<30720, 256, 0, stream>>>();
    rmat_kernel<<<(Bn * Gg * Gg + 255) / 256, 256, 0, stream>>>();
    sinkhorn_kernel<<<Bn, 512, 0, stream>>>(gumbel);
    sort_kernel<<<dim3(Bn * BLt, 2, 2), 256, 0, stream>>>();
    attn_mfma_kernel<<<Bn * Gg, 256, 0, stream>>>();
    opv_kernel<<<dim3(Bn * BLt, 2), 256, 0, stream>>>(out);
    vlast_kernel<<<Bn * BLt, 256, 0, stream>>>(v, out);
}